// Round 2
// baseline (62.066 us; speedup 1.0000x reference)
//
#include <hip/hip_runtime.h>

#define MAX_LEN 16384
#define RES_LEN 16372   // (16384 - 4) - 9 + 1
#define P2_LEN  1819    // stride-9 pool length
#define NG      4093    // RES_LEN / 4 output quads

__global__ __launch_bounds__(512, 4)
void derive_kernel(const float* __restrict__ x, float* __restrict__ out) {
    const int bid = blockIdx.x;
    // XCD-aware decode: the 4 channel-blocks of one batch land on the same XCD
    // (xcd = bid & 7 assumption; pure permutation -> correctness-neutral).
    const int k_  = bid >> 3;
    const int b   = ((bid & 7) << 5) | (k_ >> 2);
    const int c   = k_ & 3;

    const float*  __restrict__ xr  = x + (size_t)b * MAX_LEN;
    const float4* __restrict__ xr4 = (const float4*)xr;

    __shared__ float4 resS4[4096];          // 16384 floats; [0..16371] valid
    __shared__ float  a2S[P2_LEN + 1];
    __shared__ float  m2S[P2_LEN + 1];
    float* resS = (float*)resS4;

    const float inv9 = 1.0f / 9.0f;
    const int tid = threadIdx.x;

    // ---- Phase 1: res into LDS (telescoped 9-avg of shifted diffs) ----
    for (int g = tid; g < NG; g += 512) {
        float4 A = xr4[g], B4 = xr4[g + 1], C4 = xr4[g + 2], D4 = xr4[g + 3];
        float xv[16];
        xv[0]=A.x;  xv[1]=A.y;  xv[2]=A.z;  xv[3]=A.w;
        xv[4]=B4.x; xv[5]=B4.y; xv[6]=B4.z; xv[7]=B4.w;
        xv[8]=C4.x; xv[9]=C4.y; xv[10]=C4.z; xv[11]=C4.w;
        xv[12]=D4.x; xv[13]=D4.y; xv[14]=D4.z; xv[15]=D4.w;
        float rr[4];
        if (c == 0) {
            #pragma unroll
            for (int j = 0; j < 4; ++j) rr[j] = (xv[j+12] - xv[j+3]) * inv9;
        } else if (c == 1) {
            #pragma unroll
            for (int j = 0; j < 4; ++j) rr[j] = ((xv[j+12] + xv[j+11]) - (xv[j+3] + xv[j+2])) * inv9;
        } else if (c == 2) {
            #pragma unroll
            for (int j = 0; j < 4; ++j) rr[j] = ((xv[j+9] + xv[j+10] + xv[j+11] + xv[j+12])
                                               - (xv[j] + xv[j+1] + xv[j+2] + xv[j+3])) * inv9;
        } else {
            #pragma unroll
            for (int j = 0; j < 4; ++j) rr[j] = ((xv[j+12] - xv[j+11]) - (xv[j+3] - xv[j+2])) * inv9;
        }
        float4 rv; rv.x = rr[0]; rv.y = rr[1]; rv.z = rr[2]; rv.w = rr[3];
        resS4[g] = rv;
    }
    __syncthreads();

    // ---- Phase 2: stride-9 pools (lane stride 9 -> conflict-free-ish) ----
    for (int p = tid; p < P2_LEN; p += 512) {
        const int j0 = 9 * p;
        float s = resS[j0], m = resS[j0];
        #pragma unroll
        for (int t = 1; t < 9; ++t) { float v = resS[j0 + t]; s += v; m = fmaxf(m, v); }
        a2S[p] = s * inv9; m2S[p] = m;
    }
    __syncthreads();

    // ---- Phase 3: 4 outputs x 4 branches per thread, float4 stores ----
    float* outBase = out + ((size_t)b * 16 + c) * RES_LEN;
    float4* o0p = (float4*)(outBase);
    float4* o1p = (float4*)(outBase + 4 * RES_LEN);
    float4* o2p = (float4*)(outBase + 8 * RES_LEN);
    float4* o3p = (float4*)(outBase + 12 * RES_LEN);

    for (int g = tid; g < NG; g += 512) {
        const unsigned i0 = 4u * (unsigned)g;
        const unsigned p1_0 = (i0 * 16364u) / 16372u;
        const unsigned p1_1 = ((i0 + 1u) * 16364u) / 16372u;
        const unsigned p1_2 = ((i0 + 2u) * 16364u) / 16372u;
        const unsigned p1_3 = ((i0 + 3u) * 16364u) / 16372u;
        const unsigned p2_0 = (i0 * 1819u) / 16372u;
        const unsigned p2_1 = ((i0 + 1u) * 1819u) / 16372u;
        const unsigned p2_2 = ((i0 + 2u) * 1819u) / 16372u;
        const unsigned p2_3 = ((i0 + 3u) * 1819u) / 16372u;
        const unsigned q  = p1_0 >> 2;          // float4-aligned window base
        const unsigned o0 = p1_0 & 3u;          // window offsets in w[], o_k in [0, 3+k]
        const unsigned o1 = p1_1 - 4u * q;
        const unsigned o2 = p1_2 - 4u * q;
        const unsigned o3 = p1_3 - 4u * q;

        float4 W0 = resS4[q], W1 = resS4[q + 1], W2 = resS4[q + 2], W3 = resS4[q + 3];
        float w[16];
        w[0]=W0.x;  w[1]=W0.y;  w[2]=W0.z;  w[3]=W0.w;
        w[4]=W1.x;  w[5]=W1.y;  w[6]=W1.z;  w[7]=W1.w;
        w[8]=W2.x;  w[9]=W2.y;  w[10]=W2.z; w[11]=W2.w;
        w[12]=W3.x; w[13]=W3.y; w[14]=W3.z; w[15]=W3.w;

        // sliding 9-sums: s_[e] = sum(w[e .. e+8]), e = 0..6
        float s_[7];
        s_[0] = ((((((((w[0] + w[1]) + w[2]) + w[3]) + w[4]) + w[5]) + w[6]) + w[7]) + w[8]);
        #pragma unroll
        for (int e = 1; e < 7; ++e) s_[e] = s_[e - 1] - w[e - 1] + w[e + 8];

        // 9-maxes via suffix/prefix around pivot 8: m_[o] = max(w[o..o+8])
        float suf[7];
        suf[6] = fmaxf(fmaxf(w[6], w[7]), w[8]);
        #pragma unroll
        for (int t = 5; t >= 0; --t) suf[t] = fmaxf(w[t], suf[t + 1]);
        float pre[15];
        pre[8] = w[8];
        #pragma unroll
        for (int u = 9; u < 15; ++u) pre[u] = fmaxf(pre[u - 1], w[u]);
        float m_[7];
        #pragma unroll
        for (int o = 0; o < 7; ++o) m_[o] = fmaxf(suf[o], pre[o + 8]);

        // branch-free select by runtime offset (static array indices only)
        float sum0 = s_[0], sum1 = s_[0], sum2 = s_[0], sum3 = s_[0];
        float mx0  = m_[0], mx1  = m_[0], mx2  = m_[0], mx3  = m_[0];
        #pragma unroll
        for (int e = 1; e <= 3; ++e) { bool t_ = (o0 >= (unsigned)e); sum0 = t_ ? s_[e] : sum0; mx0 = t_ ? m_[e] : mx0; }
        #pragma unroll
        for (int e = 1; e <= 4; ++e) { bool t_ = (o1 >= (unsigned)e); sum1 = t_ ? s_[e] : sum1; mx1 = t_ ? m_[e] : mx1; }
        #pragma unroll
        for (int e = 1; e <= 5; ++e) { bool t_ = (o2 >= (unsigned)e); sum2 = t_ ? s_[e] : sum2; mx2 = t_ ? m_[e] : mx2; }
        #pragma unroll
        for (int e = 1; e <= 6; ++e) { bool t_ = (o3 >= (unsigned)e); sum3 = t_ ? s_[e] : sum3; mx3 = t_ ? m_[e] : mx3; }

        const float4 R = resS4[g];  // res[i0 .. i0+3]

        const float a2l = a2S[p2_0], a2h = a2S[p2_3];
        const float m2l = m2S[p2_0], m2h = m2S[p2_3];
        const float a2_1 = (p2_1 != p2_0) ? a2h : a2l;
        const float a2_2 = (p2_2 != p2_0) ? a2h : a2l;
        const float m2_1 = (p2_1 != p2_0) ? m2h : m2l;
        const float m2_2 = (p2_2 != p2_0) ? m2h : m2l;

        float4 v0, v1, v2, v3;
        v0.x = sum0 * inv9 + R.x; v0.y = sum1 * inv9 + R.y; v0.z = sum2 * inv9 + R.z; v0.w = sum3 * inv9 + R.w;
        v1.x = a2l + R.x;         v1.y = a2_1 + R.y;        v1.z = a2_2 + R.z;        v1.w = a2h + R.w;
        v2.x = mx0 + R.x;         v2.y = mx1 + R.y;         v2.z = mx2 + R.z;         v2.w = mx3 + R.w;
        v3.x = m2l + R.x;         v3.y = m2_1 + R.y;        v3.z = m2_2 + R.z;        v3.w = m2h + R.w;

        o0p[g] = v0; o1p[g] = v1; o2p[g] = v2; o3p[g] = v3;
    }
}

extern "C" void kernel_launch(void* const* d_in, const int* in_sizes, int n_in,
                              void* d_out, int out_size, void* d_ws, size_t ws_size,
                              hipStream_t stream) {
    const float* x = (const float*)d_in[0];
    float* out = (float*)d_out;
    derive_kernel<<<dim3(256 * 4), dim3(512), 0, stream>>>(x, out);
}